// Round 8
// baseline (223.968 us; speedup 1.0000x reference)
//
#include <hip/hip_runtime.h>
#include <stdint.h>

#define NN 8192
#define FIN 512
#define FOUT 64
#define ALPHA 0.2f
#define TJ 512
#define NT (NN / TJ)   // 16 tiles
#define RB 32          // rows per fused block -> 256 blocks = 1/CU

typedef float f32x4 __attribute__((ext_vector_type(4)));
typedef float f32x2 __attribute__((ext_vector_type(2)));
typedef int   i32x4 __attribute__((ext_vector_type(4)));
typedef short bf16x8 __attribute__((ext_vector_type(8)));

__device__ __forceinline__ unsigned short f2bf(float f) {
  union { float f; unsigned u; } v; v.f = f;
  unsigned r = (v.u + 0x7fffu + ((v.u >> 16) & 1u)) >> 16;
  return (unsigned short)r;
}

// ---------------- Phase 1: h = x@W (fp32), f1 = h@a1, f2 = h@a2, bpack = B-fragment layout ---
// bpack[jb][cb][lane=kgrp*16+r15][e] shorts: h[j = jb*32 + kgrp*8 + e][c = cb*16 + r15]
__global__ __launch_bounds__(256) void prep_kernel(
    const float* __restrict__ x, const float* __restrict__ W,
    const float* __restrict__ a, unsigned short* __restrict__ bpack,
    float* __restrict__ f1, float* __restrict__ f2) {
  const int lane = threadIdx.x & 63;
  const int g = blockIdx.x * 4 + (threadIdx.x >> 6);  // wave id 0..1023
  const int i0 = g * 8;

  float acc[8];
#pragma unroll
  for (int r = 0; r < 8; ++r) acc[r] = 0.0f;

  for (int k = 0; k < FIN; k += 4) {
    float w0 = W[(k + 0) * FOUT + lane];
    float w1 = W[(k + 1) * FOUT + lane];
    float w2 = W[(k + 2) * FOUT + lane];
    float w3 = W[(k + 3) * FOUT + lane];
#pragma unroll
    for (int r = 0; r < 8; ++r) {
      f32x4 xv = *(const f32x4*)(x + (size_t)(i0 + r) * FIN + k);
      acc[r] = fmaf(xv[0], w0, acc[r]);
      acc[r] = fmaf(xv[1], w1, acc[r]);
      acc[r] = fmaf(xv[2], w2, acc[r]);
      acc[r] = fmaf(xv[3], w3, acc[r]);
    }
  }

  const float a1c = a[lane];
  const float a2c = a[FOUT + lane];
#pragma unroll
  for (int r = 0; r < 8; ++r) {
    float p1 = acc[r] * a1c;
    float p2 = acc[r] * a2c;
#pragma unroll
    for (int off = 32; off >= 1; off >>= 1) {
      p1 += __shfl_xor(p1, off, 64);
      p2 += __shfl_xor(p2, off, 64);
    }
    if (lane == 0) { f1[i0 + r] = p1; f2[i0 + r] = p2; }
  }

  unsigned short hs[8];
#pragma unroll
  for (int r = 0; r < 8; ++r) hs[r] = f2bf(acc[r]);
  const int jb = i0 >> 5;
  const int kg = (i0 >> 3) & 3;
  const int cb = lane >> 4;
  const int rr = lane & 15;
  *(uint4*)(bpack + ((size_t)jb * 2048 + cb * 512 + kg * 128 + rr * 8)) = *(uint4*)hs;
}

// ---------------- Phase 2: FUSED adj-stream + weights + MFMA (raw barriers, counted waits) --
// 256 blocks x 16 waves; block owns 32 rows. Wave wv: weight rows {wv, wv+16}, MFMA k-slice wv.
// __launch_bounds__(1024, 4): 1 block/CU -> 128-VGPR cap -> no spills (r7 spilled at 64).
__global__ __launch_bounds__(1024, 4) void fused_kernel(
    const int* __restrict__ adj, const unsigned short* __restrict__ bpack,
    const float* __restrict__ f1, const float* __restrict__ f2,
    float* __restrict__ out) {
  // pw dbuf: buf0 [0,32K), buf1 [32K,64K); row stride 1024B, swizzle ^((row&7)<<4)
  // epilogue alias: num[8][32][64] f32 over [0,64K); den @65536 (32 f32)
  __shared__ __align__(16) char lds[65536 + 128];

  const int tid = threadIdx.x;
  const int lane = tid & 63;
  const int wv = tid >> 6;       // 0..15
  const int rg = blockIdx.x;     // 0..255
  const int r15 = lane & 15;
  const int kgrp = lane >> 4;

  const int row0 = rg * RB + wv;
  const int row1 = row0 + 16;
  const float f1v0 = f1[row0];
  const float f1v1 = f1[row1];
  const int* adj0 = adj + (size_t)row0 * NN;
  const int* adj1 = adj + (size_t)row1 * NN;

  // LDS byte addresses ((wv+16)&7 == wv&7, so same XOR both rows)
  const int aw0 = (wv * 1024 + lane * 16) ^ ((wv & 7) << 4);
  const int aw1 = ((wv + 16) * 1024 + lane * 16) ^ ((wv & 7) << 4);
  const int ar0 = (r15 * 1024 + wv * 64 + kgrp * 16) ^ ((r15 & 7) << 4);
  const int ar1 = ((16 + r15) * 1024 + wv * 64 + kgrp * 16) ^ ((r15 & 7) << 4);

  f32x4 acc00 = {0.f,0.f,0.f,0.f}, acc01 = acc00, acc02 = acc00, acc03 = acc00;
  f32x4 acc10 = acc00, acc11 = acc00, acc12 = acc00, acc13 = acc00;
  float den0 = 0.0f, den1 = 0.0f;

  const int jl = lane * 8;   // this lane's 8 j's within a tile

  // 2-deep prefetch: set S holds tile tt, set T holds tile tt+1 (reg-rotated by 2x unroll)
  i32x4 sA0 = *(const i32x4*)(adj0 + jl);
  i32x4 sA1 = *(const i32x4*)(adj0 + jl + 4);
  i32x4 sB0 = *(const i32x4*)(adj1 + jl);
  i32x4 sB1 = *(const i32x4*)(adj1 + jl + 4);
  f32x4 sFA = *(const f32x4*)(f2 + jl);
  f32x4 sFB = *(const f32x4*)(f2 + jl + 4);
  i32x4 tA0 = *(const i32x4*)(adj0 + TJ + jl);
  i32x4 tA1 = *(const i32x4*)(adj0 + TJ + jl + 4);
  i32x4 tB0 = *(const i32x4*)(adj1 + TJ + jl);
  i32x4 tB1 = *(const i32x4*)(adj1 + TJ + jl + 4);
  f32x4 tFA = *(const f32x4*)(f2 + TJ + jl);
  f32x4 tFB = *(const f32x4*)(f2 + TJ + jl + 4);

#define FUSED_ITER(T_, CA0, CA1, CB0, CB1, CFA, CFB) do {                           \
    const int t_ = (T_);                                                            \
    /* B-frags tile t (1-deep, L2-resident; consumed after the barrier) */          \
    const unsigned short* bp = bpack + ((size_t)(t_ * 16 + wv) * 2048) + lane * 8;  \
    bf16x8 b0 = *(const bf16x8*)(bp);                                               \
    bf16x8 b1 = *(const bf16x8*)(bp + 512);                                         \
    bf16x8 b2 = *(const bf16x8*)(bp + 1024);                                        \
    bf16x8 b3 = *(const bf16x8*)(bp + 1536);                                        \
    /* weights(t) for rows {row0,row1} from tile-t regs */                          \
    unsigned short w0[8], w1[8];                                                    \
    _Pragma("unroll")                                                               \
    for (int e = 0; e < 4; ++e) {                                                   \
      float s0 = f1v0 + CFA[e];                                                     \
      float v0 = (CA0[e] > 0) ? __expf(fmaxf(s0, ALPHA * s0)) : 0.0f;               \
      den0 += v0; w0[e] = f2bf(v0);                                                 \
      float s1 = f1v1 + CFA[e];                                                     \
      float v1 = (CB0[e] > 0) ? __expf(fmaxf(s1, ALPHA * s1)) : 0.0f;               \
      den1 += v1; w1[e] = f2bf(v1);                                                 \
    }                                                                               \
    _Pragma("unroll")                                                               \
    for (int e = 0; e < 4; ++e) {                                                   \
      float s0 = f1v0 + CFB[e];                                                     \
      float v0 = (CA1[e] > 0) ? __expf(fmaxf(s0, ALPHA * s0)) : 0.0f;               \
      den0 += v0; w0[4 + e] = f2bf(v0);                                             \
      float s1 = f1v1 + CFB[e];                                                     \
      float v1 = (CB1[e] > 0) ? __expf(fmaxf(s1, ALPHA * s1)) : 0.0f;               \
      den1 += v1; w1[4 + e] = f2bf(v1);                                             \
    }                                                                               \
    /* tile-t regs now dead: issue tile t+2 into them (floats across the barrier) */\
    {                                                                               \
      const int j2 = ((t_ + 2) & (NT - 1)) * TJ + jl;                               \
      CA0 = *(const i32x4*)(adj0 + j2);                                             \
      CA1 = *(const i32x4*)(adj0 + j2 + 4);                                         \
      CB0 = *(const i32x4*)(adj1 + j2);                                             \
      CB1 = *(const i32x4*)(adj1 + j2 + 4);                                         \
      CFA = *(const f32x4*)(f2 + j2);                                               \
      CFB = *(const f32x4*)(f2 + j2 + 4);                                           \
    }                                                                               \
    char* pwb = lds + (t_ & 1) * 32768;                                             \
    *(uint4*)(pwb + aw0) = *(uint4*)w0;                                             \
    *(uint4*)(pwb + aw1) = *(uint4*)w1;                                             \
    /* raw barrier: LDS drained, VMEM queue untouched */                            \
    asm volatile("s_waitcnt lgkmcnt(0)\n\ts_barrier" ::: "memory");                 \
    bf16x8 A0 = *(bf16x8*)(pwb + ar0);                                              \
    bf16x8 A1 = *(bf16x8*)(pwb + ar1);                                              \
    acc00 = __builtin_amdgcn_mfma_f32_16x16x32_bf16(A0, b0, acc00, 0, 0, 0);        \
    acc01 = __builtin_amdgcn_mfma_f32_16x16x32_bf16(A0, b1, acc01, 0, 0, 0);        \
    acc02 = __builtin_amdgcn_mfma_f32_16x16x32_bf16(A0, b2, acc02, 0, 0, 0);        \
    acc03 = __builtin_amdgcn_mfma_f32_16x16x32_bf16(A0, b3, acc03, 0, 0, 0);        \
    acc10 = __builtin_amdgcn_mfma_f32_16x16x32_bf16(A1, b0, acc10, 0, 0, 0);        \
    acc11 = __builtin_amdgcn_mfma_f32_16x16x32_bf16(A1, b1, acc11, 0, 0, 0);        \
    acc12 = __builtin_amdgcn_mfma_f32_16x16x32_bf16(A1, b2, acc12, 0, 0, 0);        \
    acc13 = __builtin_amdgcn_mfma_f32_16x16x32_bf16(A1, b3, acc13, 0, 0, 0);        \
  } while (0)

  for (int tt = 0; tt < NT; tt += 2) {
    FUSED_ITER(tt,     sA0, sA1, sB0, sB1, sFA, sFB);
    FUSED_ITER(tt + 1, tA0, tA1, tB0, tB1, tFA, tFB);
  }
#undef FUSED_ITER

  // row denominators (full 64-lane sums; lane's j's all belong to the same row)
#pragma unroll
  for (int off = 1; off <= 32; off <<= 1) {
    den0 += __shfl_xor(den0, off, 64);
    den1 += __shfl_xor(den1, off, 64);
  }

  // all pw reads done before aliasing lds as num
  asm volatile("s_waitcnt lgkmcnt(0)\n\ts_barrier" ::: "memory");

  float* nump = (float*)lds;                 // [8][32][64]
  float* denp = (float*)(lds + 65536);       // [32]
  if (lane == 0) { denp[wv] = den0; denp[wv + 16] = den1; }

  // stage A: k-slices 0-7 write
  if (wv < 8) {
#pragma unroll
    for (int r = 0; r < 4; ++r) {
      const int rl = kgrp * 4 + r;
      nump[(wv * 32 + rl) * 64 +  0 + r15] = acc00[r];
      nump[(wv * 32 + rl) * 64 + 16 + r15] = acc01[r];
      nump[(wv * 32 + rl) * 64 + 32 + r15] = acc02[r];
      nump[(wv * 32 + rl) * 64 + 48 + r15] = acc03[r];
      nump[(wv * 32 + 16 + rl) * 64 +  0 + r15] = acc10[r];
      nump[(wv * 32 + 16 + rl) * 64 + 16 + r15] = acc11[r];
      nump[(wv * 32 + 16 + rl) * 64 + 32 + r15] = acc12[r];
      nump[(wv * 32 + 16 + rl) * 64 + 48 + r15] = acc13[r];
    }
  }
  asm volatile("s_waitcnt lgkmcnt(0)\n\ts_barrier" ::: "memory");

  // stage B: k-slices 8-15 accumulate in place
  if (wv >= 8) {
    const int s = wv - 8;
#pragma unroll
    for (int r = 0; r < 4; ++r) {
      const int rl = kgrp * 4 + r;
      nump[(s * 32 + rl) * 64 +  0 + r15] += acc00[r];
      nump[(s * 32 + rl) * 64 + 16 + r15] += acc01[r];
      nump[(s * 32 + rl) * 64 + 32 + r15] += acc02[r];
      nump[(s * 32 + rl) * 64 + 48 + r15] += acc03[r];
      nump[(s * 32 + 16 + rl) * 64 +  0 + r15] += acc10[r];
      nump[(s * 32 + 16 + rl) * 64 + 16 + r15] += acc11[r];
      nump[(s * 32 + 16 + rl) * 64 + 32 + r15] += acc12[r];
      nump[(s * 32 + 16 + rl) * 64 + 48 + r15] += acc13[r];
    }
  }
  asm volatile("s_waitcnt lgkmcnt(0)\n\ts_barrier" ::: "memory");

  // combine 8 pair-slices, divide, elu, store: 2 consecutive elems per thread
  {
    const int idx = tid * 2;
    const int orow = idx >> 6;
    const int ocol = idx & 63;
    f32x2 sv = {0.0f, 0.0f};
#pragma unroll
    for (int s = 0; s < 8; ++s) {
      sv[0] += nump[(s * 32 + orow) * 64 + ocol];
      sv[1] += nump[(s * 32 + orow) * 64 + ocol + 1];
    }
    const float d = denp[orow];
    float v0 = sv[0] / d, v1 = sv[1] / d;
    v0 = (v0 > 0.0f) ? v0 : (__expf(v0) - 1.0f);
    v1 = (v1 > 0.0f) ? v1 : (__expf(v1) - 1.0f);
    f32x2 ov = {v0, v1};
    *(f32x2*)(out + (size_t)(rg * RB + orow) * FOUT + ocol) = ov;
  }
}

extern "C" void kernel_launch(void* const* d_in, const int* in_sizes, int n_in,
                              void* d_out, int out_size, void* d_ws, size_t ws_size,
                              hipStream_t stream) {
  const float* x = (const float*)d_in[0];
  const int* adj = (const int*)d_in[1];
  const float* W = (const float*)d_in[2];
  const float* a = (const float*)d_in[3];
  float* out = (float*)d_out;

  char* ws = (char*)d_ws;
  unsigned short* bpack = (unsigned short*)ws;                 // 1 MB
  float* f1 = (float*)(ws + (size_t)FOUT * NN * 2);            // 32 KB
  float* f2 = f1 + NN;                                         // 32 KB

  hipLaunchKernelGGL(prep_kernel, dim3(256), dim3(256), 0, stream, x, W, a, bpack, f1, f2);
  hipLaunchKernelGGL(fused_kernel, dim3(NN / RB), dim3(1024), 0, stream,
                     adj, bpack, f1, f2, out);
}

// Round 9
// 118.630 us; speedup vs baseline: 1.8880x; 1.8880x over previous
//
#include <hip/hip_runtime.h>
#include <stdint.h>

#define NN 8192
#define FIN 512
#define FOUT 64
#define ALPHA 0.2f
#define TJ 512
#define NT (NN / TJ)   // 16 tiles
#define RB 16          // rows per fused block -> 512 blocks

typedef float f32x4 __attribute__((ext_vector_type(4)));
typedef float f32x2 __attribute__((ext_vector_type(2)));
typedef int   i32x4 __attribute__((ext_vector_type(4)));
typedef short bf16x8 __attribute__((ext_vector_type(8)));

__device__ __forceinline__ unsigned short f2bf(float f) {
  union { float f; unsigned u; } v; v.f = f;
  unsigned r = (v.u + 0x7fffu + ((v.u >> 16) & 1u)) >> 16;
  return (unsigned short)r;
}

// ---------------- Phase 1: h = x@W (fp32), f1 = h@a1, f2 = h@a2, bpack = B-fragment layout ---
// bpack[jb][cb][lane=kgrp*16+r15][e] shorts: h[j = jb*32 + kgrp*8 + e][c = cb*16 + r15]
__global__ __launch_bounds__(256) void prep_kernel(
    const float* __restrict__ x, const float* __restrict__ W,
    const float* __restrict__ a, unsigned short* __restrict__ bpack,
    float* __restrict__ f1, float* __restrict__ f2) {
  const int lane = threadIdx.x & 63;
  const int g = blockIdx.x * 4 + (threadIdx.x >> 6);  // wave id 0..1023
  const int i0 = g * 8;

  float acc[8];
#pragma unroll
  for (int r = 0; r < 8; ++r) acc[r] = 0.0f;

  for (int k = 0; k < FIN; k += 4) {
    float w0 = W[(k + 0) * FOUT + lane];
    float w1 = W[(k + 1) * FOUT + lane];
    float w2 = W[(k + 2) * FOUT + lane];
    float w3 = W[(k + 3) * FOUT + lane];
#pragma unroll
    for (int r = 0; r < 8; ++r) {
      f32x4 xv = *(const f32x4*)(x + (size_t)(i0 + r) * FIN + k);
      acc[r] = fmaf(xv[0], w0, acc[r]);
      acc[r] = fmaf(xv[1], w1, acc[r]);
      acc[r] = fmaf(xv[2], w2, acc[r]);
      acc[r] = fmaf(xv[3], w3, acc[r]);
    }
  }

  const float a1c = a[lane];
  const float a2c = a[FOUT + lane];
#pragma unroll
  for (int r = 0; r < 8; ++r) {
    float p1 = acc[r] * a1c;
    float p2 = acc[r] * a2c;
#pragma unroll
    for (int off = 32; off >= 1; off >>= 1) {
      p1 += __shfl_xor(p1, off, 64);
      p2 += __shfl_xor(p2, off, 64);
    }
    if (lane == 0) { f1[i0 + r] = p1; f2[i0 + r] = p2; }
  }

  unsigned short hs[8];
#pragma unroll
  for (int r = 0; r < 8; ++r) hs[r] = f2bf(acc[r]);
  const int jb = i0 >> 5;
  const int kg = (i0 >> 3) & 3;
  const int cb = lane >> 4;
  const int rr = lane & 15;
  *(uint4*)(bpack + ((size_t)jb * 2048 + cb * 512 + kg * 128 + rr * 8)) = *(uint4*)hs;
}

// ---------------- Phase 2: FUSED adj-stream + weights + MFMA --------------------------------
// 512 blocks x 16 waves; block owns 16 rows. Wave wv: weight row wv, MFMA k-slice wv (K=32).
// amdgpu_waves_per_eu(4,4): 4 waves/EU -> 128-reg budget (r8 spilled at the default 64 cap).
// Raw s_barrier (lgkmcnt only) keeps adj/f2/bpack prefetches in flight across barriers.
__global__ __launch_bounds__(1024) __attribute__((amdgpu_waves_per_eu(4, 4)))
void fused_kernel(
    const int* __restrict__ adj, const unsigned short* __restrict__ bpack,
    const float* __restrict__ f1, const float* __restrict__ f2,
    float* __restrict__ out) {
  // pw dbuf: buf0 [0,16K), buf1 [16K,32K); row stride 1024B, swizzle ^((row&7)<<4)
  // epilogue alias: num[8][16][64] f32 over [0,32K); den @32768 (16 f32)
  __shared__ __align__(16) char lds[32768 + 64];

  const int tid = threadIdx.x;
  const int lane = tid & 63;
  const int wv = tid >> 6;       // 0..15
  const int rg = blockIdx.x;     // 0..511
  const int r15 = lane & 15;
  const int kgrp = lane >> 4;

  const int row0 = rg * RB + wv;
  const float f1v0 = f1[row0];
  const int* adj0 = adj + (size_t)row0 * NN;

  const int aw = (wv * 1024 + lane * 16) ^ ((wv & 7) << 4);
  const int ar = (r15 * 1024 + wv * 64 + kgrp * 16) ^ ((r15 & 7) << 4);

  f32x4 acc0 = {0.f, 0.f, 0.f, 0.f};
  f32x4 acc1 = acc0, acc2 = acc0, acc3 = acc0;
  float den = 0.0f;

  const int jl = lane * 8;   // this lane's 8 j's within a tile (lane*8 .. +7)

  // 2-deep prefetch: set S = tile tt, set T = tile tt+1 (reg-rotated by 2x unroll)
  i32x4 sA0 = *(const i32x4*)(adj0 + jl);
  i32x4 sA1 = *(const i32x4*)(adj0 + jl + 4);
  f32x4 sFA = *(const f32x4*)(f2 + jl);
  f32x4 sFB = *(const f32x4*)(f2 + jl + 4);
  i32x4 tA0 = *(const i32x4*)(adj0 + TJ + jl);
  i32x4 tA1 = *(const i32x4*)(adj0 + TJ + jl + 4);
  f32x4 tFA = *(const f32x4*)(f2 + TJ + jl);
  f32x4 tFB = *(const f32x4*)(f2 + TJ + jl + 4);

#define FUSED_ITER(T_, CA0, CA1, CFA, CFB) do {                                     \
    const int t_ = (T_);                                                            \
    /* B-frags tile t (issued early; consumed after the barrier) */                 \
    const unsigned short* bp = bpack + ((size_t)(t_ * 16 + wv) * 2048) + lane * 8;  \
    bf16x8 b0 = *(const bf16x8*)(bp);                                               \
    bf16x8 b1 = *(const bf16x8*)(bp + 512);                                         \
    bf16x8 b2 = *(const bf16x8*)(bp + 1024);                                        \
    bf16x8 b3 = *(const bf16x8*)(bp + 1536);                                        \
    /* weights(t) for row wv from tile-t regs */                                    \
    unsigned short w8[8];                                                           \
    _Pragma("unroll")                                                               \
    for (int e = 0; e < 4; ++e) {                                                   \
      float s0 = f1v0 + CFA[e];                                                     \
      float v0 = (CA0[e] > 0) ? __expf(fmaxf(s0, ALPHA * s0)) : 0.0f;               \
      den += v0; w8[e] = f2bf(v0);                                                  \
    }                                                                               \
    _Pragma("unroll")                                                               \
    for (int e = 0; e < 4; ++e) {                                                   \
      float s0 = f1v0 + CFB[e];                                                     \
      float v0 = (CA1[e] > 0) ? __expf(fmaxf(s0, ALPHA * s0)) : 0.0f;               \
      den += v0; w8[4 + e] = f2bf(v0);                                              \
    }                                                                               \
    /* tile-t regs now dead: issue tile t+2 into them (floats across barriers) */   \
    {                                                                               \
      const int j2 = ((t_ + 2) & (NT - 1)) * TJ + jl;                               \
      CA0 = *(const i32x4*)(adj0 + j2);                                             \
      CA1 = *(const i32x4*)(adj0 + j2 + 4);                                         \
      CFA = *(const f32x4*)(f2 + j2);                                               \
      CFB = *(const f32x4*)(f2 + j2 + 4);                                           \
    }                                                                               \
    char* pwb = lds + (t_ & 1) * 16384;                                             \
    *(uint4*)(pwb + aw) = *(uint4*)w8;                                              \
    /* raw barrier: LDS drained, VMEM queue untouched */                            \
    asm volatile("s_waitcnt lgkmcnt(0)\n\ts_barrier" ::: "memory");                 \
    bf16x8 A0 = *(bf16x8*)(pwb + ar);                                               \
    acc0 = __builtin_amdgcn_mfma_f32_16x16x32_bf16(A0, b0, acc0, 0, 0, 0);          \
    acc1 = __builtin_amdgcn_mfma_f32_16x16x32_bf16(A0, b1, acc1, 0, 0, 0);          \
    acc2 = __builtin_amdgcn_mfma_f32_16x16x32_bf16(A0, b2, acc2, 0, 0, 0);          \
    acc3 = __builtin_amdgcn_mfma_f32_16x16x32_bf16(A0, b3, acc3, 0, 0, 0);          \
  } while (0)

  for (int tt = 0; tt < NT; tt += 2) {
    FUSED_ITER(tt,     sA0, sA1, sFA, sFB);
    FUSED_ITER(tt + 1, tA0, tA1, tFA, tFB);
  }
#undef FUSED_ITER

  // row denominator (wave wv owns row wv's entire j-range)
#pragma unroll
  for (int off = 1; off <= 32; off <<= 1) den += __shfl_xor(den, off, 64);

  // all pw reads done before aliasing lds as num
  asm volatile("s_waitcnt lgkmcnt(0)\n\ts_barrier" ::: "memory");

  float* nump = (float*)lds;                 // [8][16][64]
  float* denp = (float*)(lds + 32768);       // [16]
  if (lane == 0) denp[wv] = den;

  // stage A: k-slices 0-7 write
  if (wv < 8) {
#pragma unroll
    for (int r = 0; r < 4; ++r) {
      const int rl = kgrp * 4 + r;
      nump[(wv * 16 + rl) * 64 +  0 + r15] = acc0[r];
      nump[(wv * 16 + rl) * 64 + 16 + r15] = acc1[r];
      nump[(wv * 16 + rl) * 64 + 32 + r15] = acc2[r];
      nump[(wv * 16 + rl) * 64 + 48 + r15] = acc3[r];
    }
  }
  asm volatile("s_waitcnt lgkmcnt(0)\n\ts_barrier" ::: "memory");

  // stage B: k-slices 8-15 accumulate in place
  if (wv >= 8) {
    const int s = wv - 8;
#pragma unroll
    for (int r = 0; r < 4; ++r) {
      const int rl = kgrp * 4 + r;
      nump[(s * 16 + rl) * 64 +  0 + r15] += acc0[r];
      nump[(s * 16 + rl) * 64 + 16 + r15] += acc1[r];
      nump[(s * 16 + rl) * 64 + 32 + r15] += acc2[r];
      nump[(s * 16 + rl) * 64 + 48 + r15] += acc3[r];
    }
  }
  asm volatile("s_waitcnt lgkmcnt(0)\n\ts_barrier" ::: "memory");

  // combine 8 pair-slices, divide, elu, store: one element per thread
  {
    const int orow = tid >> 6;
    const int ocol = tid & 63;
    float s = 0.0f;
#pragma unroll
    for (int k = 0; k < 8; ++k) s += nump[(k * 16 + orow) * 64 + ocol];
    float v = s / denp[orow];
    out[(size_t)(rg * RB + orow) * FOUT + ocol] = (v > 0.0f) ? v : (__expf(v) - 1.0f);
  }
}

extern "C" void kernel_launch(void* const* d_in, const int* in_sizes, int n_in,
                              void* d_out, int out_size, void* d_ws, size_t ws_size,
                              hipStream_t stream) {
  const float* x = (const float*)d_in[0];
  const int* adj = (const int*)d_in[1];
  const float* W = (const float*)d_in[2];
  const float* a = (const float*)d_in[3];
  float* out = (float*)d_out;

  char* ws = (char*)d_ws;
  unsigned short* bpack = (unsigned short*)ws;                 // 1 MB
  float* f1 = (float*)(ws + (size_t)FOUT * NN * 2);            // 32 KB
  float* f2 = f1 + NN;                                         // 32 KB

  hipLaunchKernelGGL(prep_kernel, dim3(256), dim3(256), 0, stream, x, W, a, bpack, f1, f2);
  hipLaunchKernelGGL(fused_kernel, dim3(NN / RB), dim3(1024), 0, stream,
                     adj, bpack, f1, f2, out);
}

// Round 11
// 109.253 us; speedup vs baseline: 2.0500x; 1.0858x over previous
//
#include <hip/hip_runtime.h>
#include <stdint.h>

#define NN 8192
#define FIN 512
#define FOUT 64
#define ALPHA 0.2f
#define TJ 512
#define NT (NN / TJ)   // 16 tiles
#define RB 16          // rows per fused block -> 512 blocks

typedef float f32x4 __attribute__((ext_vector_type(4)));
typedef int   i32x4 __attribute__((ext_vector_type(4)));
typedef short bf16x8 __attribute__((ext_vector_type(8)));

__device__ __forceinline__ unsigned short f2bf(float f) {
  union { float f; unsigned u; } v; v.f = f;
  unsigned r = (v.u + 0x7fffu + ((v.u >> 16) & 1u)) >> 16;
  return (unsigned short)r;
}

// ---------------- Phase 1: h = x@W (fp32), f1 = h@a1, f2 = h@a2, bpack = B-fragment layout ---
__global__ __launch_bounds__(256) void prep_kernel(
    const float* __restrict__ x, const float* __restrict__ W,
    const float* __restrict__ a, unsigned short* __restrict__ bpack,
    float* __restrict__ f1, float* __restrict__ f2) {
  const int lane = threadIdx.x & 63;
  const int g = blockIdx.x * 4 + (threadIdx.x >> 6);  // wave id 0..1023
  const int i0 = g * 8;

  float acc[8];
#pragma unroll
  for (int r = 0; r < 8; ++r) acc[r] = 0.0f;

  for (int k = 0; k < FIN; k += 4) {
    float w0 = W[(k + 0) * FOUT + lane];
    float w1 = W[(k + 1) * FOUT + lane];
    float w2 = W[(k + 2) * FOUT + lane];
    float w3 = W[(k + 3) * FOUT + lane];
#pragma unroll
    for (int r = 0; r < 8; ++r) {
      f32x4 xv = *(const f32x4*)(x + (size_t)(i0 + r) * FIN + k);
      acc[r] = fmaf(xv[0], w0, acc[r]);
      acc[r] = fmaf(xv[1], w1, acc[r]);
      acc[r] = fmaf(xv[2], w2, acc[r]);
      acc[r] = fmaf(xv[3], w3, acc[r]);
    }
  }

  const float a1c = a[lane];
  const float a2c = a[FOUT + lane];
#pragma unroll
  for (int r = 0; r < 8; ++r) {
    float p1 = acc[r] * a1c;
    float p2 = acc[r] * a2c;
#pragma unroll
    for (int off = 32; off >= 1; off >>= 1) {
      p1 += __shfl_xor(p1, off, 64);
      p2 += __shfl_xor(p2, off, 64);
    }
    if (lane == 0) { f1[i0 + r] = p1; f2[i0 + r] = p2; }
  }

  unsigned short hs[8];
#pragma unroll
  for (int r = 0; r < 8; ++r) hs[r] = f2bf(acc[r]);
  const int jb = i0 >> 5;
  const int kg = (i0 >> 3) & 3;
  const int cb = lane >> 4;
  const int rr = lane & 15;
  *(uint4*)(bpack + ((size_t)jb * 2048 + cb * 512 + kg * 128 + rr * 8)) = *(uint4*)hs;
}

// ---------------- Phase 2: FUSED adj-stream + weights + MFMA --------------------------------
// 512 blocks x 16 waves; block owns 16 rows (XCD-swizzled). Wave wv: weight row wv, MFMA
// k-slice wv (K=32). Raw s_barrier (lgkmcnt only) keeps adj/f2/bpack loads in flight.
// r9 structure exactly; ONLY delta = XCD-bijective rg remap.
__global__ __launch_bounds__(1024) __attribute__((amdgpu_waves_per_eu(4, 4)))
void fused_kernel(
    const int* __restrict__ adj, const unsigned short* __restrict__ bpack,
    const float* __restrict__ f1, const float* __restrict__ f2,
    float* __restrict__ out) {
  // pw dbuf: buf0 [0,16K), buf1 [16K,32K); row stride 1024B, swizzle ^((row&7)<<4)
  // epilogue alias: num[8][16][64] f32 over [0,32K); den @32768 (16 f32)
  __shared__ __align__(16) char lds[32768 + 64];

  const int tid = threadIdx.x;
  const int lane = tid & 63;
  const int wv = tid >> 6;       // 0..15
  // XCD-bijective swizzle (512 % 8 == 0): each XCD walks one contiguous adj window
  const int rg = (blockIdx.x & 7) * 64 + (blockIdx.x >> 3);   // 0..511
  const int r15 = lane & 15;
  const int kgrp = lane >> 4;

  const int row0 = rg * RB + wv;
  const float f1v0 = f1[row0];
  const int* adj0 = adj + (size_t)row0 * NN;

  const int aw = (wv * 1024 + lane * 16) ^ ((wv & 7) << 4);
  const int ar = (r15 * 1024 + wv * 64 + kgrp * 16) ^ ((r15 & 7) << 4);

  f32x4 acc0 = {0.f, 0.f, 0.f, 0.f};
  f32x4 acc1 = acc0, acc2 = acc0, acc3 = acc0;
  float den = 0.0f;

  const int jl = lane * 8;   // this lane's 8 j's within a tile (lane*8 .. +7)

  // 2-deep prefetch: set S = tile tt, set T = tile tt+1 (reg-rotated by 2x unroll)
  i32x4 sA0 = *(const i32x4*)(adj0 + jl);
  i32x4 sA1 = *(const i32x4*)(adj0 + jl + 4);
  f32x4 sFA = *(const f32x4*)(f2 + jl);
  f32x4 sFB = *(const f32x4*)(f2 + jl + 4);
  i32x4 tA0 = *(const i32x4*)(adj0 + TJ + jl);
  i32x4 tA1 = *(const i32x4*)(adj0 + TJ + jl + 4);
  f32x4 tFA = *(const f32x4*)(f2 + TJ + jl);
  f32x4 tFB = *(const f32x4*)(f2 + TJ + jl + 4);

#define FUSED_ITER(T_, CA0, CA1, CFA, CFB) do {                                     \
    const int t_ = (T_);                                                            \
    /* B-frags tile t (issued early; consumed after the barrier) */                 \
    const unsigned short* bp = bpack + ((size_t)(t_ * 16 + wv) * 2048) + lane * 8;  \
    bf16x8 b0 = *(const bf16x8*)(bp);                                               \
    bf16x8 b1 = *(const bf16x8*)(bp + 512);                                         \
    bf16x8 b2 = *(const bf16x8*)(bp + 1024);                                        \
    bf16x8 b3 = *(const bf16x8*)(bp + 1536);                                        \
    /* weights(t) for row wv from tile-t regs */                                    \
    unsigned short w8[8];                                                           \
    _Pragma("unroll")                                                               \
    for (int e = 0; e < 4; ++e) {                                                   \
      float s0 = f1v0 + CFA[e];                                                     \
      float v0 = (CA0[e] > 0) ? __expf(fmaxf(s0, ALPHA * s0)) : 0.0f;               \
      den += v0; w8[e] = f2bf(v0);                                                  \
    }                                                                               \
    _Pragma("unroll")                                                               \
    for (int e = 0; e < 4; ++e) {                                                   \
      float s0 = f1v0 + CFB[e];                                                     \
      float v0 = (CA1[e] > 0) ? __expf(fmaxf(s0, ALPHA * s0)) : 0.0f;               \
      den += v0; w8[4 + e] = f2bf(v0);                                              \
    }                                                                               \
    /* tile-t regs now dead: issue tile t+2 into them (floats across barriers) */   \
    {                                                                               \
      const int j2 = ((t_ + 2) & (NT - 1)) * TJ + jl;                               \
      CA0 = *(const i32x4*)(adj0 + j2);                                             \
      CA1 = *(const i32x4*)(adj0 + j2 + 4);                                         \
      CFA = *(const f32x4*)(f2 + j2);                                               \
      CFB = *(const f32x4*)(f2 + j2 + 4);                                           \
    }                                                                               \
    char* pwb = lds + (t_ & 1) * 16384;                                             \
    *(uint4*)(pwb + aw) = *(uint4*)w8;                                              \
    /* raw barrier: LDS drained, VMEM queue untouched */                            \
    asm volatile("s_waitcnt lgkmcnt(0)\n\ts_barrier" ::: "memory");                 \
    bf16x8 A0 = *(bf16x8*)(pwb + ar);                                               \
    acc0 = __builtin_amdgcn_mfma_f32_16x16x32_bf16(A0, b0, acc0, 0, 0, 0);          \
    acc1 = __builtin_amdgcn_mfma_f32_16x16x32_bf16(A0, b1, acc1, 0, 0, 0);          \
    acc2 = __builtin_amdgcn_mfma_f32_16x16x32_bf16(A0, b2, acc2, 0, 0, 0);          \
    acc3 = __builtin_amdgcn_mfma_f32_16x16x32_bf16(A0, b3, acc3, 0, 0, 0);          \
  } while (0)

  for (int tt = 0; tt < NT; tt += 2) {
    FUSED_ITER(tt,     sA0, sA1, sFA, sFB);
    FUSED_ITER(tt + 1, tA0, tA1, tFA, tFB);
  }
#undef FUSED_ITER

  // row denominator (wave wv owns row wv's entire j-range)
#pragma unroll
  for (int off = 1; off <= 32; off <<= 1) den += __shfl_xor(den, off, 64);

  // all pw reads done before aliasing lds as num
  asm volatile("s_waitcnt lgkmcnt(0)\n\ts_barrier" ::: "memory");

  float* nump = (float*)lds;                 // [8][16][64]
  float* denp = (float*)(lds + 32768);       // [16]
  if (lane == 0) denp[wv] = den;

  // stage A: k-slices 0-7 write
  if (wv < 8) {
#pragma unroll
    for (int r = 0; r < 4; ++r) {
      const int rl = kgrp * 4 + r;
      nump[(wv * 16 + rl) * 64 +  0 + r15] = acc0[r];
      nump[(wv * 16 + rl) * 64 + 16 + r15] = acc1[r];
      nump[(wv * 16 + rl) * 64 + 32 + r15] = acc2[r];
      nump[(wv * 16 + rl) * 64 + 48 + r15] = acc3[r];
    }
  }
  asm volatile("s_waitcnt lgkmcnt(0)\n\ts_barrier" ::: "memory");

  // stage B: k-slices 8-15 accumulate in place
  if (wv >= 8) {
    const int s = wv - 8;
#pragma unroll
    for (int r = 0; r < 4; ++r) {
      const int rl = kgrp * 4 + r;
      nump[(s * 16 + rl) * 64 +  0 + r15] += acc0[r];
      nump[(s * 16 + rl) * 64 + 16 + r15] += acc1[r];
      nump[(s * 16 + rl) * 64 + 32 + r15] += acc2[r];
      nump[(s * 16 + rl) * 64 + 48 + r15] += acc3[r];
    }
  }
  asm volatile("s_waitcnt lgkmcnt(0)\n\ts_barrier" ::: "memory");

  // combine 8 pair-slices, divide, elu, store: one element per thread
  {
    const int orow = tid >> 6;
    const int ocol = tid & 63;
    float s = 0.0f;
#pragma unroll
    for (int k = 0; k < 8; ++k) s += nump[(k * 16 + orow) * 64 + ocol];
    float v = s / denp[orow];
    out[(size_t)(rg * RB + orow) * FOUT + ocol] = (v > 0.0f) ? v : (__expf(v) - 1.0f);
  }
}

extern "C" void kernel_launch(void* const* d_in, const int* in_sizes, int n_in,
                              void* d_out, int out_size, void* d_ws, size_t ws_size,
                              hipStream_t stream) {
  const float* x = (const float*)d_in[0];
  const int* adj = (const int*)d_in[1];
  const float* W = (const float*)d_in[2];
  const float* a = (const float*)d_in[3];
  float* out = (float*)d_out;

  char* ws = (char*)d_ws;
  unsigned short* bpack = (unsigned short*)ws;                 // 1 MB
  float* f1 = (float*)(ws + (size_t)FOUT * NN * 2);            // 32 KB
  float* f2 = f1 + NN;                                         // 32 KB

  hipLaunchKernelGGL(prep_kernel, dim3(256), dim3(256), 0, stream, x, W, a, bpack, f1, f2);
  hipLaunchKernelGGL(fused_kernel, dim3(NN / RB), dim3(1024), 0, stream,
                     adj, bpack, f1, f2, out);
}